// Round 7
// baseline (452.234 us; speedup 1.0000x reference)
//
#include <hip/hip_runtime.h>
#include <math.h>

#define BB 8
#define LL 2048
#define DM 256
#define NH 8
#define DH 32
#define DFF 1024
#define SS 40
#define UU 40
#define BL (BB*LL)   // 16384
#define NSL 8        // attnupd L-slices per (b,h)

// attnupd LDS layout constants
#define KP  40       // k/q row stride (ushorts) — 16B-aligned rows for b128
#define VTP 264      // transposed-V / P row stride (ushorts): b128-aligned, ~2-way banks

typedef unsigned short ushort_t;
typedef unsigned char uchar_t;
typedef __attribute__((ext_vector_type(8))) short short8;
typedef __attribute__((ext_vector_type(4))) float f32x4;

__device__ inline ushort_t f2b(float f)
{
    unsigned int u = __float_as_uint(f);
    u += 0x7fff + ((u >> 16) & 1);      // round-to-nearest-even
    return (ushort_t)(u >> 16);
}

__device__ inline float blo(unsigned int u) { return __uint_as_float(u << 16); }
__device__ inline float bhi(unsigned int u) { return __uint_as_float(u & 0xffff0000u); }

__device__ inline void gload16(const void* g, const void* l)
{
    __builtin_amdgcn_global_load_lds(
        (const __attribute__((address_space(1))) unsigned int*)g,
        (__attribute__((address_space(3))) unsigned int*)l, 16, 0, 0);
}

// ---------------------------------------------------------------------------
// bf16 MFMA GEMM, m97 structure. 128x128 tile, BK=32, 256 thr.
// Kept ONLY for the K=32 input projection (K not a multiple of 64).
// OUT_MODE: 0 fp32 RM | 1 QKV scatter | 2 bf16 RM | 3 fp32 RM + bf16 aux
// ---------------------------------------------------------------------------
template<int RELU, int OUT_MODE>
__global__ __launch_bounds__(256)
void gemm_mfma(const ushort_t* __restrict__ A, const ushort_t* __restrict__ Bt,
               const float* __restrict__ bias, void* __restrict__ Cout,
               void* __restrict__ aux, int M, int N, int K)
{
    __shared__ ushort_t Asl[128 * 32];
    __shared__ ushort_t Bsl[128 * 32];

    const int t    = threadIdx.x;
    const int lane = t & 63;
    const int wv   = t >> 6;
    const int row0 = blockIdx.x * 128;
    const int col0 = blockIdx.y * 128;
    const int wr   = (wv >> 1) * 64;
    const int wc   = (wv & 1) * 64;
    const int quad = lane >> 4;
    const int l16  = lane & 15;

    f32x4 acc[4][4];
    #pragma unroll
    for (int i = 0; i < 4; ++i)
        #pragma unroll
        for (int j = 0; j < 4; ++j)
            acc[i][j] = 0.f;

    for (int k0 = 0; k0 < K; k0 += 32) {
        __syncthreads();
        #pragma unroll
        for (int r = 0; r < 2; ++r) {
            int g = r * 256 + t;
            const ushort_t* ga = A  + (size_t)(row0 + (g >> 2)) * K + k0 + (g & 3) * 8;
            const ushort_t* gb = Bt + (size_t)(col0 + (g >> 2)) * K + k0 + (g & 3) * 8;
            int lbase = (r * 256 + wv * 64) * 16;
            gload16(ga, (const char*)Asl + lbase);
            gload16(gb, (const char*)Bsl + lbase);
        }
        __syncthreads();

        short8 af[4], bfr[4];
        #pragma unroll
        for (int mi = 0; mi < 4; ++mi)
            af[mi] = *(const short8*)&Asl[(wr + mi * 16 + l16) * 32 + quad * 8];
        #pragma unroll
        for (int ni = 0; ni < 4; ++ni)
            bfr[ni] = *(const short8*)&Bsl[(wc + ni * 16 + l16) * 32 + quad * 8];
        #pragma unroll
        for (int mi = 0; mi < 4; ++mi)
            #pragma unroll
            for (int ni = 0; ni < 4; ++ni)
                acc[mi][ni] = __builtin_amdgcn_mfma_f32_16x16x32_bf16(
                    af[mi], bfr[ni], acc[mi][ni], 0, 0, 0);
    }

    #pragma unroll
    for (int mi = 0; mi < 4; ++mi) {
        #pragma unroll
        for (int ni = 0; ni < 4; ++ni) {
            int col = col0 + wc + ni * 16 + l16;
            float bb = bias[col];
            #pragma unroll
            for (int r = 0; r < 4; ++r) {
                int row = row0 + wr + mi * 16 + quad * 4 + r;
                float v = acc[mi][ni][r] + bb;
                if (RELU) v = v > 0.f ? v : 0.f;
                if (OUT_MODE == 0) {
                    ((float*)Cout)[(size_t)row * N + col] = v;
                } else if (OUT_MODE == 1) {
                    int tensor = col >> 8;          // 0=q 1=k 2=v
                    int c2 = col & 255;
                    int b  = row >> 11, l = row & (LL - 1);
                    int hh = c2 >> 5,  dh = c2 & 31;
                    int bh = b * NH + hh;
                    size_t bi = (((size_t)bh * LL + l) << 5) + dh;
                    ushort_t vb16 = f2b(v);
                    ((ushort_t*)Cout)[(size_t)tensor * (BB*NH*LL*DH) + bi] = vb16;
                    if (tensor == 1)   // kT[l][bh][d] bf16 for metric
                        ((ushort_t*)aux)[(((size_t)l << 6) + bh) * 32 + dh] = vb16;
                } else if (OUT_MODE == 2) {
                    ((ushort_t*)Cout)[(size_t)row * N + col] = f2b(v);
                } else {
                    ((float*)Cout)[(size_t)row * N + col] = v;
                    ((ushort_t*)aux)[(size_t)row * N + col] = f2b(v);
                }
            }
        }
    }
}

// ---------------------------------------------------------------------------
// gemm_pipe: 128x128 tile, BK=64, dbuf LDS (64 KB, 2 blk/CU) with COUNTED
// vmcnt + raw s_barrier (T3+T4): next tile's 8 gload16/thread stay in flight
// across the barrier. T2 XOR swizzle both-sides. Requires K % 64 == 0.
// ---------------------------------------------------------------------------
template<int RELU, int OUT_MODE>
__global__ __launch_bounds__(256)
void gemm_pipe(const ushort_t* __restrict__ A, const ushort_t* __restrict__ Bt,
               const float* __restrict__ bias, void* __restrict__ Cout,
               void* __restrict__ aux, int M, int N, int K)
{
    __shared__ ushort_t Asl[2][128 * 64];   // 16 KB x2
    __shared__ ushort_t Bsl[2][128 * 64];   // 16 KB x2

    const int t    = threadIdx.x;
    const int lane = t & 63;
    const int wv   = t >> 6;
    const int row0 = blockIdx.x * 128;
    const int col0 = blockIdx.y * 128;
    const int wr   = (wv >> 1) * 64;
    const int wc   = (wv & 1) * 64;
    const int quad = lane >> 4;
    const int l16  = lane & 15;

    f32x4 acc[4][4];
    #pragma unroll
    for (int i = 0; i < 4; ++i)
        #pragma unroll
        for (int j = 0; j < 4; ++j)
            acc[i][j] = 0.f;

    auto stage = [&](int bf, int k0) {
        #pragma unroll
        for (int r = 0; r < 4; ++r) {
            int gg = r * 256 + t;
            int row = gg >> 3, c8 = gg & 7;
            const ushort_t* ga =
                A + (size_t)(row0 + row) * K + k0 + ((c8 ^ (row & 7)) * 8);
            gload16(ga, (const char*)&Asl[bf][0] + (r * 256 + wv * 64) * 16);
        }
        #pragma unroll
        for (int r = 0; r < 4; ++r) {
            int gg = r * 256 + t;
            int row = gg >> 3, c8 = gg & 7;
            const ushort_t* gb =
                Bt + (size_t)(col0 + row) * K + k0 + ((c8 ^ (row & 7)) * 8);
            gload16(gb, (const char*)&Bsl[bf][0] + (r * 256 + wv * 64) * 16);
        }
    };

    const int NS = K >> 6;
    stage(0, 0);

    for (int ks = 0; ks < NS; ++ks) {
        int cur = ks & 1;
        if (ks + 1 < NS) {
            stage(cur ^ 1, (ks + 1) << 6);      // 8 new loads in flight
            asm volatile("s_waitcnt vmcnt(8)" ::: "memory");  // prev tile done
        } else {
            asm volatile("s_waitcnt vmcnt(0)" ::: "memory");
        }
        __builtin_amdgcn_sched_barrier(0);
        __builtin_amdgcn_s_barrier();           // raw: no drain

        #pragma unroll
        for (int kk = 0; kk < 2; ++kk) {
            short8 af[4], bfr[4];
            #pragma unroll
            for (int mi = 0; mi < 4; ++mi) {
                int row = wr + mi * 16 + l16;
                af[mi] = *(const short8*)
                    &Asl[cur][row * 64 + (((kk * 4 + quad) ^ (row & 7)) * 8)];
            }
            #pragma unroll
            for (int ni = 0; ni < 4; ++ni) {
                int row = wc + ni * 16 + l16;
                bfr[ni] = *(const short8*)
                    &Bsl[cur][row * 64 + (((kk * 4 + quad) ^ (row & 7)) * 8)];
            }
            #pragma unroll
            for (int mi = 0; mi < 4; ++mi)
                #pragma unroll
                for (int ni = 0; ni < 4; ++ni)
                    acc[mi][ni] = __builtin_amdgcn_mfma_f32_16x16x32_bf16(
                        af[mi], bfr[ni], acc[mi][ni], 0, 0, 0);
        }

        __builtin_amdgcn_sched_barrier(0);
        __builtin_amdgcn_s_barrier();           // protect cur buf from restage
    }

    #pragma unroll
    for (int mi = 0; mi < 4; ++mi) {
        #pragma unroll
        for (int ni = 0; ni < 4; ++ni) {
            int col = col0 + wc + ni * 16 + l16;
            float bb = bias[col];
            #pragma unroll
            for (int r = 0; r < 4; ++r) {
                int row = row0 + wr + mi * 16 + quad * 4 + r;
                float v = acc[mi][ni][r] + bb;
                if (RELU) v = v > 0.f ? v : 0.f;
                if (OUT_MODE == 0) {
                    ((float*)Cout)[(size_t)row * N + col] = v;
                } else if (OUT_MODE == 1) {
                    int tensor = col >> 8;          // 0=q 1=k 2=v
                    int c2 = col & 255;
                    int b  = row >> 11, l = row & (LL - 1);
                    int hh = c2 >> 5,  dh = c2 & 31;
                    int bh = b * NH + hh;
                    size_t bi = (((size_t)bh * LL + l) << 5) + dh;
                    ushort_t vb16 = f2b(v);
                    ((ushort_t*)Cout)[(size_t)tensor * (BB*NH*LL*DH) + bi] = vb16;
                    if (tensor == 1)   // kT[l][bh][d] bf16 for metric
                        ((ushort_t*)aux)[(((size_t)l << 6) + bh) * 32 + dh] = vb16;
                } else if (OUT_MODE == 2) {
                    ((ushort_t*)Cout)[(size_t)row * N + col] = f2b(v);
                } else {
                    ((float*)Cout)[(size_t)row * N + col] = v;
                    ((ushort_t*)aux)[(size_t)row * N + col] = f2b(v);
                }
            }
        }
    }
}

// ---------------------------------------------------------------------------
// Fused GEMM (Mx256, K=256) + residual + LayerNorm (LN1 only):
//   h = LN(h + A@Bt^T + bias) * g + beta ; writes h fp32 + hb bf16.
// 32x256 tile, BK=64, grid M/32 = 512 (2 blocks/CU), counted vmcnt pipeline.
// ---------------------------------------------------------------------------
template<int HEAD>
__global__ __launch_bounds__(256)
void gemmln_k(const ushort_t* __restrict__ A, const ushort_t* __restrict__ Bt,
              const float* __restrict__ bias, float* __restrict__ h,
              ushort_t* __restrict__ hb, const float* __restrict__ g,
              const float* __restrict__ beta, int K,
              const float* __restrict__ w1, const float* __restrict__ b1,
              const float* __restrict__ w2, const float* __restrict__ b2,
              float* __restrict__ out)
{
    __shared__ ushort_t Asl[2][32 * 64];    // 4 KB x2
    __shared__ ushort_t Bsl[2][256 * 64];   // 32 KB x2
    __shared__ float rs[4][32], rs2[4][32]; // 1 KB
    __shared__ float hrowS[256];

    const int t    = threadIdx.x;
    const int lane = t & 63;
    const int wv   = t >> 6;
    const int row0 = blockIdx.x * 32;
    const int wc   = wv * 64;
    const int quad = lane >> 4;
    const int l16  = lane & 15;

    // --- prologue loads (issued before staging: keeps loop vmcnt exact) ---
    float gcol[4], bcol[4], bic[4];
    float hres[2][4][4];
    #pragma unroll
    for (int ni = 0; ni < 4; ++ni) {
        int col = wc + ni * 16 + l16;
        gcol[ni] = g[col];
        bcol[ni] = beta[col];
        bic[ni]  = bias[col];
    }
    #pragma unroll
    for (int mi = 0; mi < 2; ++mi)
        #pragma unroll
        for (int r = 0; r < 4; ++r) {
            int row = row0 + mi * 16 + quad * 4 + r;
            #pragma unroll
            for (int ni = 0; ni < 4; ++ni)
                hres[mi][r][ni] = h[(size_t)row * DM + wc + ni * 16 + l16];
        }

    f32x4 acc[2][4];
    #pragma unroll
    for (int i = 0; i < 2; ++i)
        #pragma unroll
        for (int j = 0; j < 4; ++j)
            acc[i][j] = 0.f;

    // 9 uniform gload16 per thread: 1 A-chunk + 8 B-chunks.
    auto stage = [&](int bf, int k0) {
        {
            int row = t >> 3, c8 = t & 7;
            const ushort_t* ga =
                A + (size_t)(row0 + row) * K + k0 + ((c8 ^ (row & 7)) * 8);
            gload16(ga, (const char*)&Asl[bf][0] + (wv * 64) * 16);
        }
        #pragma unroll
        for (int r = 0; r < 8; ++r) {
            int gg = r * 256 + t;
            int row = gg >> 3, c8 = gg & 7;
            const ushort_t* gb =
                Bt + (size_t)row * K + k0 + ((c8 ^ (row & 7)) * 8);
            gload16(gb, (const char*)&Bsl[bf][0] + (r * 256 + wv * 64) * 16);
        }
    };

    const int NS = K >> 6;
    stage(0, 0);

    for (int ks = 0; ks < NS; ++ks) {
        int cur = ks & 1;
        if (ks + 1 < NS) {
            stage(cur ^ 1, (ks + 1) << 6);      // 9 new loads in flight
            asm volatile("s_waitcnt vmcnt(9)" ::: "memory");  // prev tile done
        } else {
            asm volatile("s_waitcnt vmcnt(0)" ::: "memory");
        }
        __builtin_amdgcn_sched_barrier(0);
        __builtin_amdgcn_s_barrier();           // raw: no drain

        short8 af[2][2], bfr[4][2];
        #pragma unroll
        for (int mi = 0; mi < 2; ++mi) {
            int row = mi * 16 + l16;
            #pragma unroll
            for (int kk = 0; kk < 2; ++kk)
                af[mi][kk] = *(const short8*)
                    &Asl[cur][row * 64 + (((kk * 4 + quad) ^ (row & 7)) * 8)];
        }
        #pragma unroll
        for (int ni = 0; ni < 4; ++ni) {
            int row = wc + ni * 16 + l16;
            #pragma unroll
            for (int kk = 0; kk < 2; ++kk)
                bfr[ni][kk] = *(const short8*)
                    &Bsl[cur][row * 64 + (((kk * 4 + quad) ^ (row & 7)) * 8)];
        }
        #pragma unroll
        for (int kk = 0; kk < 2; ++kk)
            #pragma unroll
            for (int mi = 0; mi < 2; ++mi)
                #pragma unroll
                for (int ni = 0; ni < 4; ++ni)
                    acc[mi][ni] = __builtin_amdgcn_mfma_f32_16x16x32_bf16(
                        af[mi][kk], bfr[ni][kk], acc[mi][ni], 0, 0, 0);

        __builtin_amdgcn_sched_barrier(0);
        __builtin_amdgcn_s_barrier();           // protect cur buf from restage
    }

    // --- epilogue: residual + LN ---
    float ps[2][4], ps2[2][4];
    #pragma unroll
    for (int mi = 0; mi < 2; ++mi) {
        #pragma unroll
        for (int r = 0; r < 4; ++r) {
            float s = 0.f, s2 = 0.f;
            #pragma unroll
            for (int ni = 0; ni < 4; ++ni) {
                float v = acc[mi][ni][r] + bic[ni] + hres[mi][r][ni];
                acc[mi][ni][r] = v;
                s += v;
                s2 += v * v;
            }
            ps[mi][r] = s;
            ps2[mi][r] = s2;
        }
    }
    #pragma unroll
    for (int off = 1; off < 16; off <<= 1) {
        #pragma unroll
        for (int mi = 0; mi < 2; ++mi)
            #pragma unroll
            for (int r = 0; r < 4; ++r) {
                ps[mi][r]  += __shfl_xor(ps[mi][r],  off, 16);
                ps2[mi][r] += __shfl_xor(ps2[mi][r], off, 16);
            }
    }
    if (l16 == 0) {
        #pragma unroll
        for (int mi = 0; mi < 2; ++mi)
            #pragma unroll
            for (int r = 0; r < 4; ++r) {
                int lrow = mi * 16 + quad * 4 + r;
                rs[wv][lrow]  = ps[mi][r];
                rs2[wv][lrow] = ps2[mi][r];
            }
    }
    __syncthreads();

    #pragma unroll
    for (int mi = 0; mi < 2; ++mi) {
        #pragma unroll
        for (int r = 0; r < 4; ++r) {
            int lrow = mi * 16 + quad * 4 + r;
            int row  = row0 + lrow;
            float tot  = rs[0][lrow] + rs[1][lrow] + rs[2][lrow] + rs[3][lrow];
            float tot2 = rs2[0][lrow] + rs2[1][lrow] + rs2[2][lrow] + rs2[3][lrow];
            float mean = tot * (1.f / (float)DM);
            float var  = tot2 * (1.f / (float)DM) - mean * mean;
            float inv  = 1.0f / sqrtf(var + 1e-5f);
            #pragma unroll
            for (int ni = 0; ni < 4; ++ni) {
                int col = wc + ni * 16 + l16;
                float val = (acc[mi][ni][r] - mean) * inv * gcol[ni] + bcol[ni];
                h[(size_t)row * DM + col]  = val;
                hb[(size_t)row * DM + col] = f2b(val);
                if (HEAD && lrow == 31) hrowS[col] = val;   // last row of block
            }
        }
    }

    if (HEAD) {
        __syncthreads();
        if ((blockIdx.x & 63) == 63 && t < 64) {
            int b = blockIdx.x >> 6;
            float s = 0.f;
            for (int kk = 0; kk < DM; ++kk)
                s = fmaf(hrowS[kk], w1[kk * 64 + t], s);
            s += b1[t];
            s = s > 0.f ? s : 0.f;
            float contrib = s * w2[t];
            #pragma unroll
            for (int off = 32; off > 0; off >>= 1)
                contrib += __shfl_down(contrib, off, 64);
            if (t == 0) out[b] = contrib + b2[0];
        }
    }
}

// ---------------------------------------------------------------------------
// lnfin: streaming residual + LayerNorm finish for the split-K LN2 path.
//   h = LN(h + C) * g + beta  (bias already folded into C by gemm_pipe).
// Block = 64 rows; one wave per row per pass (16 passes of 4 rows); full-row
// reduce via 64-lane shfl. Optional MLP head on the 8 per-batch last rows.
// ---------------------------------------------------------------------------
template<int HEAD>
__global__ __launch_bounds__(256)
void lnfin_k(const float* __restrict__ C, float* __restrict__ h,
             ushort_t* __restrict__ hb, const float* __restrict__ g,
             const float* __restrict__ beta,
             const float* __restrict__ w1, const float* __restrict__ b1,
             const float* __restrict__ w2, const float* __restrict__ b2,
             float* __restrict__ out)
{
    __shared__ float hrowS[256];
    const int t    = threadIdx.x;
    const int lane = t & 63;
    const int wv   = t >> 6;
    const int row0 = blockIdx.x * 64;

    float4 gv = ((const float4*)g)[lane];
    float4 bv = ((const float4*)beta)[lane];

    #pragma unroll 4
    for (int pass = 0; pass < 16; ++pass) {
        int row = row0 + pass * 4 + wv;
        float4 c  = ((const float4*)(C + (size_t)row * DM))[lane];
        float4 hr = ((const float4*)(h + (size_t)row * DM))[lane];
        float4 v;
        v.x = c.x + hr.x; v.y = c.y + hr.y;
        v.z = c.z + hr.z; v.w = c.w + hr.w;
        float s  = v.x + v.y + v.z + v.w;
        float s2 = v.x * v.x + v.y * v.y + v.z * v.z + v.w * v.w;
        #pragma unroll
        for (int off = 32; off > 0; off >>= 1) {
            s  += __shfl_xor(s,  off, 64);
            s2 += __shfl_xor(s2, off, 64);
        }
        float mean = s * (1.f / (float)DM);
        float var  = s2 * (1.f / (float)DM) - mean * mean;
        float inv  = 1.0f / sqrtf(var + 1e-5f);
        v.x = (v.x - mean) * inv * gv.x + bv.x;
        v.y = (v.y - mean) * inv * gv.y + bv.y;
        v.z = (v.z - mean) * inv * gv.z + bv.z;
        v.w = (v.w - mean) * inv * gv.w + bv.w;
        ((float4*)(h + (size_t)row * DM))[lane] = v;
        unsigned int lo = (unsigned int)f2b(v.x) | ((unsigned int)f2b(v.y) << 16);
        unsigned int hi = (unsigned int)f2b(v.z) | ((unsigned int)f2b(v.w) << 16);
        ((uint2*)(hb + (size_t)row * DM))[lane] = make_uint2(lo, hi);
        if (HEAD && ((blockIdx.x & 31) == 31) && pass == 15 && wv == 3)
            ((float4*)hrowS)[lane] = v;    // row b*2048+2047
    }

    if (HEAD) {
        __syncthreads();
        if ((blockIdx.x & 31) == 31 && t < 64) {
            int b = blockIdx.x >> 5;
            float s = 0.f;
            for (int kk = 0; kk < DM; ++kk)
                s = fmaf(hrowS[kk], w1[kk * 64 + t], s);
            s += b1[t];
            s = s > 0.f ? s : 0.f;
            float contrib = s * w2[t];
            #pragma unroll
            for (int off = 32; off > 0; off >>= 1)
                contrib += __shfl_down(contrib, off, 64);
            if (t == 0) out[b] = contrib + b2[0];
        }
    }
}

// ---------------------------------------------------------------------------
// fused preproc: all weight transposes+cvt, bias pack, x cvt in ONE dispatch.
// ---------------------------------------------------------------------------
__device__ inline void tcvt_dev(float (*tile)[33], const float* __restrict__ src,
                                ushort_t* __restrict__ dst, int K, int N,
                                int matStride, int bi)
{
    int tilesN = N >> 5;
    int tpm = (K >> 5) * tilesN;
    int m   = bi / tpm;
    int tid = bi % tpm;
    int k0 = (tid / tilesN) << 5, n0 = (tid % tilesN) << 5;
    const float* s = src + (size_t)m * K * N;
    ushort_t*    d = dst + (size_t)m * matStride;
    int r = threadIdx.x >> 5, c = threadIdx.x & 31;
    #pragma unroll
    for (int i = 0; i < 4; ++i)
        tile[r + 8 * i][c] = s[(size_t)(k0 + r + 8 * i) * N + n0 + c];
    __syncthreads();
    #pragma unroll
    for (int i = 0; i < 4; ++i)
        d[(size_t)(n0 + r + 8 * i) * K + k0 + c] = f2b(tile[c][r + 8 * i]);
}

__global__ __launch_bounds__(256)
void preproc_k(const float* __restrict__ wq, const float* __restrict__ wk,
               const float* __restrict__ wv, const float* __restrict__ wo,
               const float* __restrict__ wf1, const float* __restrict__ wf2,
               const float* __restrict__ w_in,
               const float* __restrict__ bq, const float* __restrict__ bk,
               const float* __restrict__ bv, const float* __restrict__ x,
               ushort_t* __restrict__ wqkvT, ushort_t* __restrict__ woT,
               ushort_t* __restrict__ wf1T, ushort_t* __restrict__ wf2T,
               ushort_t* __restrict__ w_inT, float* __restrict__ bqkv,
               ushort_t* __restrict__ xb16)
{
    __shared__ float tile[32][33];
    int b = blockIdx.x;
    if (b < 512) {
        int which = b >> 7, lb = b & 127;
        const float* src = which == 0 ? wq : which == 1 ? wk : which == 2 ? wv : wo;
        ushort_t* dst = which == 0 ? wqkvT : which == 1 ? wqkvT + 65536
                       : which == 2 ? wqkvT + 131072 : woT;
        int stride = which == 3 ? 65536 : 768 * 256;
        tcvt_dev(tile, src, dst, DM, DM, stride, lb);
    } else if (b < 1024) {
        tcvt_dev(tile, wf1, wf1T, DM, DFF, 1024 * 256, b - 512);
    } else if (b < 1536) {
        tcvt_dev(tile, wf2, wf2T, DFF, DM, 256 * 1024, b - 1024);
    } else if (b < 1544) {
        tcvt_dev(tile, w_in, w_inT, 32, DM, 256 * 32, b - 1536);
    } else if (b < 1550) {
        int t = (b - 1544) * 256 + threadIdx.x;
        int i = t / 768, j = t % 768;
        const float* s = j < 256 ? bq : (j < 512 ? bk : bv);
        bqkv[t] = s[i * 256 + (j & 255)];
    } else {
        int tid = (b - 1550) * 256 + threadIdx.x;
        float4 v = ((const float4*)x)[tid];
        unsigned int lo = f2b(v.x) | ((unsigned int)f2b(v.y) << 16);
        unsigned int hi = f2b(v.z) | ((unsigned int)f2b(v.w) << 16);
        ((uint2*)xb16)[tid] = make_uint2(lo, hi);
    }
}

// ---------------------------------------------------------------------------
// metric v6: split-s. 8 waves/block (512 thr): wave (wl, half) computes l =
// blk*4+wl over s-half; partial (max, sum) merged via LDS. grid 512 x 512.
// ---------------------------------------------------------------------------
__global__ __launch_bounds__(512)
void metric2_k(const ushort_t* __restrict__ qb16, const ushort_t* __restrict__ kT,
               const int* __restrict__ idx, float* __restrict__ Mout,
               unsigned int* __restrict__ jidx32)
{
    __shared__ float mxS[2][4][64];
    __shared__ float smS[2][4][64];
    int t = threadIdx.x;
    int w = t >> 6, lane = t & 63;
    int wl = w & 3, half = w >> 2;
    int l = blockIdx.x * 4 + wl;

    if (t < 64) {
        int zb = t >> 3, sel = t & 7;
        int zl = blockIdx.x * 4 + (sel >> 1), hf = sel & 1;
        jidx32[(size_t)(zb * LL + zl) * 2 + hf] = 0;
    }

    float4 q[8];
    {
        const uint4* qr4 = (const uint4*)(qb16 + ((size_t)(lane * LL + l) << 5));
        #pragma unroll
        for (int i = 0; i < 4; ++i) {
            uint4 u = qr4[i];
            q[2 * i]     = make_float4(blo(u.x), bhi(u.x), blo(u.y), bhi(u.y));
            q[2 * i + 1] = make_float4(blo(u.z), bhi(u.z), blo(u.w), bhi(u.w));
        }
    }

    int r40 = idx[l * SS + (lane < SS ? lane : SS - 1)];

    float mx = -3e38f, sm = 0.f;
    int sBeg = half * 20;
    #pragma unroll 4
    for (int s = sBeg; s < sBeg + 20; ++s) {
        int r = __shfl(r40, s, 64);
        const uint4* kr = (const uint4*)(kT + (((size_t)r << 6) + lane) * 32);
        float d = 0.f;
        #pragma unroll
        for (int ww = 0; ww < 4; ++ww) {
            uint4 kv = kr[ww];
            float4 qa = q[2 * ww], qb2 = q[2 * ww + 1];
            d = fmaf(blo(kv.x), qa.x, d);
            d = fmaf(bhi(kv.x), qa.y, d);
            d = fmaf(blo(kv.y), qa.z, d);
            d = fmaf(bhi(kv.y), qa.w, d);
            d = fmaf(blo(kv.z), qb2.x, d);
            d = fmaf(bhi(kv.z), qb2.y, d);
            d = fmaf(blo(kv.w), qb2.z, d);
            d = fmaf(bhi(kv.w), qb2.w, d);
        }
        mx = fmaxf(mx, d);
        sm += d;
    }
    mxS[half][wl][lane] = mx;
    smS[half][wl][lane] = sm;
    __syncthreads();

    if (t < 256) {
        int bh = t >> 2, ls = t & 3;
        float m = fmaxf(mxS[0][ls][bh], mxS[1][ls][bh]);
        float s = smS[0][ls][bh] + smS[1][ls][bh];
        Mout[(size_t)bh * LL + blockIdx.x * 4 + ls] = m - s * (1.0f / (float)LL);
    }
}

// ---------------------------------------------------------------------------
// topkf v2: stage 1 all-pairs rank-select (64 shfl-rotation steps); identical
// selected set to the serial argmax (same strict total order). Stage 2:
// in-LDS rank-select over the 320 candidates.
// ---------------------------------------------------------------------------
__global__ __launch_bounds__(512)
void topkf_k(const float* __restrict__ Mout, int* __restrict__ top,
             uchar_t* __restrict__ jidx)
{
    __shared__ float cvS[320];
    __shared__ int   ciS[320];
    int bh = blockIdx.x;
    int t  = threadIdx.x;
    int lane = t & 63, w = t >> 6;   // w = slice 0..7
    int l0 = w << 8;

    float v[4];
    #pragma unroll
    for (int i = 0; i < 4; ++i)
        v[i] = Mout[(size_t)bh * LL + l0 + i * 64 + lane];

    int rank[4] = {0, 0, 0, 0};
    for (int step = 0; step < 64; ++step) {
        int src = (lane + step) & 63;
        #pragma unroll
        for (int j = 0; j < 4; ++j) {
            float ov = __shfl(v[j], src, 64);
            int   oi = l0 + j * 64 + src;
            #pragma unroll
            for (int i = 0; i < 4; ++i) {
                int mi = l0 + i * 64 + lane;
                rank[i] += (ov > v[i]) || (ov == v[i] && oi < mi);
            }
        }
    }
    #pragma unroll
    for (int i = 0; i < 4; ++i) {
        if (rank[i] < UU) {
            cvS[w * UU + rank[i]] = v[i];
            ciS[w * UU + rank[i]] = l0 + i * 64 + lane;
        }
    }
    __syncthreads();

    for (int c = t; c < 320; c += 512) {
        float mv = cvS[c]; int mi = ciS[c];
        int rnk = 0;
        for (int j = 0; j < 320; ++j)
            rnk += (cvS[j] > mv) || (cvS[j] == mv && ciS[j] < mi);
        if (rnk < UU) {
            top[bh * UU + rnk] = mi;
            int b = bh >> 3, hh = bh & 7;
            jidx[(size_t)(b * LL + mi) * 8 + hh] = (uchar_t)(rnk + 1);
        }
    }
}

// ---------------------------------------------------------------------------
// attnupd v8: REGISTER softmax. QK^T scores stay in VGPRs (dd[3][4] f32x4 =
// exactly the MFMA output); row-max via 16-lane shfl + 4x48 LDS merge (max is
// order-invariant -> bitwise-identical m); exp in registers; P written ONCE
// as bf16 [48][VTP] (25 KB); row sums via shfl + 4x48 merge. Removes the old
// 50 KB fp32 sc buffer and its 4 LDS passes: LDS 75.6 -> 51.6 KB, occupancy
// 2 -> 3 blocks/CU. P values bitwise identical to v7 (same scores, same max,
// same expf, same f2b); sP summation order differs sub-ulp.
// ---------------------------------------------------------------------------
__global__ __launch_bounds__(256)
void attnupd_k(const ushort_t* __restrict__ qb16, const ushort_t* __restrict__ kb16,
               const ushort_t* __restrict__ vb16, const int* __restrict__ top,
               float* __restrict__ mP, float* __restrict__ sP,
               float* __restrict__ OP, float* __restrict__ vmeanP)
{
    __shared__ ushort_t qs[48 * KP];     // 3.84 KB (rows 40..47 zero)
    __shared__ ushort_t kv[256 * KP];    // 20 KB (K stride KP; later vT 32xVTP)
    __shared__ ushort_t Pl[48 * VTP];    // 25.3 KB bf16 P
    __shared__ float    wredS[4][48];    // per-wave row partials
    __shared__ float    msh[48];
    __shared__ float    red[8][32];

    int blk = blockIdx.x;
    int sl  = blk & (NSL - 1);
    int bh  = blk >> 3;
    int t   = threadIdx.x;
    int l0  = sl << 8;
    int lane = t & 63, wvx = t >> 6;
    int quad = lane >> 4, l16 = lane & 15;
    const float scale = 0.17677669529663687f;   // 1/sqrt(32)

    // stage q_top bf16 (zero-pad rows 40..47) and k slice bf16
    for (int i = t; i < 48 * 32; i += 256) {
        int j = i >> 5, dcol = i & 31;
        qs[j * KP + dcol] = (j < UU)
            ? qb16[((size_t)(bh * LL + top[bh * UU + j]) << 5) + dcol] : (ushort_t)0;
    }
    {
        const unsigned int* krow =
            (const unsigned int*)(kb16 + ((size_t)(bh * LL + l0 + t) << 5));
        #pragma unroll
        for (int i = 0; i < 16; ++i)
            ((unsigned int*)kv)[t * (KP / 2) + i] = krow[i];
    }
    __syncthreads();

    // QK^T into registers: wave wvx covers N-tiles wvx*4..+3, M-tiles 0..2
    f32x4 dd[3][4];
    {
        short8 afq[3];
        #pragma unroll
        for (int mt = 0; mt < 3; ++mt)
            afq[mt] = *(const short8*)&qs[(mt * 16 + l16) * KP + quad * 8];
        #pragma unroll
        for (int n4 = 0; n4 < 4; ++n4) {
            int nt = wvx * 4 + n4;
            short8 bk = *(const short8*)&kv[(nt * 16 + l16) * KP + quad * 8];
            #pragma unroll
            for (int mt = 0; mt < 3; ++mt) {
                f32x4 z = {0.f, 0.f, 0.f, 0.f};
                dd[mt][n4] = __builtin_amdgcn_mfma_f32_16x16x32_bf16(
                    afq[mt], bk, z, 0, 0, 0);
            }
        }
    }
    // scale + per-row partial max (over this wave's 64 cols)
    float pm[3][4];
    #pragma unroll
    for (int mt = 0; mt < 3; ++mt) {
        #pragma unroll
        for (int n4 = 0; n4 < 4; ++n4)
            dd[mt][n4] *= scale;
        #pragma unroll
        for (int r = 0; r < 4; ++r)
            pm[mt][r] = fmaxf(fmaxf(dd[mt][0][r], dd[mt][1][r]),
                              fmaxf(dd[mt][2][r], dd[mt][3][r]));
    }
    #pragma unroll
    for (int off = 8; off > 0; off >>= 1)
        #pragma unroll
        for (int mt = 0; mt < 3; ++mt)
            #pragma unroll
            for (int r = 0; r < 4; ++r)
                pm[mt][r] = fmaxf(pm[mt][r], __shfl_xor(pm[mt][r], off, 16));
    if (l16 == 0) {
        #pragma unroll
        for (int mt = 0; mt < 3; ++mt)
            #pragma unroll
            for (int r = 0; r < 4; ++r)
                wredS[wvx][mt * 16 + quad * 4 + r] = pm[mt][r];
    }
    __syncthreads();
    if (t < 48)
        msh[t] = fmaxf(fmaxf(wredS[0][t], wredS[1][t]),
                       fmaxf(wredS[2][t], wredS[3][t]));
    __syncthreads();

    // exp in regs -> P bf16 write; row-sum partials; V transpose; vmean
    float ps[3][4];
    #pragma unroll
    for (int mt = 0; mt < 3; ++mt) {
        #pragma unroll
        for (int r = 0; r < 4; ++r) {
            int row = mt * 16 + quad * 4 + r;
            float mm = msh[row];
            float s = 0.f;
            #pragma unroll
            for (int n4 = 0; n4 < 4; ++n4) {
                float e = __expf(dd[mt][n4][r] - mm);
                Pl[row * VTP + wvx * 64 + n4 * 16 + l16] = f2b(e);
                s += e;
            }
            ps[mt][r] = s;
        }
    }
    #pragma unroll
    for (int off = 1; off < 16; off <<= 1)
        #pragma unroll
        for (int mt = 0; mt < 3; ++mt)
            #pragma unroll
            for (int r = 0; r < 4; ++r)
                ps[mt][r] += __shfl_xor(ps[mt][r], off, 16);
    if (l16 == 0) {
        #pragma unroll
        for (int mt = 0; mt < 3; ++mt)
            #pragma unroll
            for (int r = 0; r < 4; ++r)
                wredS[wvx][mt * 16 + quad * 4 + r] = ps[mt][r];
    }
    int j8 = t >> 5, d = t & 31;
    {
        const unsigned int* vrow =
            (const unsigned int*)(vb16 + ((size_t)(bh * LL + l0 + t) << 5));
        #pragma unroll
        for (int i = 0; i < 16; ++i) {
            unsigned int u = vrow[i];
            kv[(2 * i)     * VTP + t] = (ushort_t)(u & 0xffffu);
            kv[(2 * i + 1) * VTP + t] = (ushort_t)(u >> 16);
        }
        const ushort_t* base = vb16 + ((size_t)(bh * LL + l0 + j8 * 32) << 5) + d;
        float s = 0.f;
        #pragma unroll 8
        for (int i = 0; i < 32; ++i)
            s += __uint_as_float((unsigned int)base[(size_t)i << 5] << 16);
        red[j8][d] = s;
    }
    __syncthreads();

    int pq = bh * NSL + sl;
    if (t < UU) {
        sP[pq * UU + t] = (wredS[0][t] + wredS[1][t]) + (wredS[2][t] + wredS[3][t]);
        mP[pq * UU + t] = msh[t];
    }
    if (t < 32) {
        float tot = 0.f;
        #pragma unroll
        for (int p = 0; p < 8; ++p) tot += red[p][t];
        vmeanP[pq * 32 + t] = tot;
    }

    // PV MFMA: waves 0..2 handle M-tile wvx, N = 32 d (2 tiles), K = 256 l
    if (wvx < 3) {
        f32x4 acc0 = {0.f, 0.f, 0.f, 0.f};
        f32x4 acc1 = {0.f, 0.f, 0.f, 0.f};
        #pragma unroll
        for (int ks = 0; ks < 8; ++ks) {
            short8 af = *(const short8*)
                &Pl[(wvx * 16 + l16) * VTP + ks * 32 + quad * 8];
            #pragma unroll
            for (int nt = 0; nt < 2; ++nt) {
                short8 bf = *(const short8*)
                    &kv[(nt * 16 + l16) * VTP + ks * 32 + quad * 8];
                if (nt == 0)
                    acc0 = __builtin_amdgcn_mfma_f32_16x16x32_bf16(af, bf, acc0, 0, 0, 0);
                else
                    acc1 = __builtin_amdgcn_mfma_f32_16x16x32_bf16(af, bf, acc1, 0, 0, 0);
            }
        }
        #pragma unroll
        for (int r = 0; r < 4; ++r) {
            int j = wvx * 16 + quad * 4 + r;
            if (j < UU) {
                OP[((size_t)pq * UU + j) * 32 + l16]      = acc0[r];
                OP[((size_t)pq * UU + j) * 32 + 16 + l16] = acc1[r];
            }
        }
    }
}

// ---------------------------------------------------------------------------
// fillcomb v2: block = (bh, 256-row slice) -> 512 blocks. vmean total summed
// ONCE per block into LDS; rows broadcast from LDS; rare j!=0 rows keep the
// exact old merge path.
// ---------------------------------------------------------------------------
__global__ __launch_bounds__(256)
void fillcomb_k(const float* __restrict__ vmeanP, const uchar_t* __restrict__ jidx,
                const float* __restrict__ mP, const float* __restrict__ sP,
                const float* __restrict__ OP, ushort_t* __restrict__ ctxb)
{
    __shared__ float vs[32];
    int blk = blockIdx.x;
    int bh  = blk >> 3;           // 0..63
    int sl  = blk & 7;
    int l0  = sl << 8;
    int b   = bh >> 3, hh = bh & 7;
    int t   = threadIdx.x;

    if (t < 32) {
        float s = 0.f;
        #pragma unroll
        for (int q = 0; q < NSL; ++q)
            s += vmeanP[(bh * NSL + q) * 32 + t];
        vs[t] = s * (1.f / (float)LL);
    }
    __syncthreads();

    int p  = t & 15;              // pair index within 32-d block
    int d0 = p * 2;
    #pragma unroll 4
    for (int it = 0; it < 16; ++it) {
        int lr   = it * 16 + (t >> 4);             // 0..255
        int rowi = (b << 11) + l0 + lr;            // b*2048 + l
        int j    = (int)jidx[(size_t)rowi * 8 + hh];

        float v0, v1;
        if (j == 0) {
            v0 = vs[d0];
            v1 = vs[d0 + 1];
        } else {
            int jj = j - 1;
            float M = -3e38f;
            #pragma unroll
            for (int q = 0; q < NSL; ++q) M = fmaxf(M, mP[(bh * NSL + q) * UU + jj]);
            float S = 0.f, O0 = 0.f, O1 = 0.f;
            #pragma unroll
            for (int q = 0; q < NSL; ++q) {
                float wgt = __expf(mP[(bh * NSL + q) * UU + jj] - M);
                S  = fmaf(sP[(bh * NSL + q) * UU + jj], wgt, S);
                O0 = fmaf(OP[((size_t)(bh * NSL + q) * UU + jj) * 32 + d0], wgt, O0);
                O1 = fmaf(OP[((size_t)(bh * NSL + q) * UU + jj) * 32 + d0 + 1], wgt, O1);
            }
            v0 = O0 / S;
            v1 = O1 / S;
        }
        ((unsigned int*)ctxb)[(size_t)rowi * 128 + hh * 16 + p] =
            (unsigned int)f2b(v0) | ((unsigned int)f2b(v1) << 16);
    }
}

extern "C" void kernel_launch(void* const* d_in, const int* in_sizes, int n_in,
                              void* d_out, int out_size, void* d_ws, size_t ws_size,
                              hipStream_t stream)
{
    const float* x    = (const float*)d_in[0];
    const int*   idx  = (const int*)  d_in[1];
    const float* w_in = (const float*)d_in[2];
    const float* b_in = (const float*)d_in[3];
    const float* wq   = (const float*)d_in[4];
    const float* bq   = (const float*)d_in[5];
    const float* wk   = (const float*)d_in[6];
    const float* bk   = (const float*)d_in[7];
    const float* wv   = (const float*)d_in[8];
    const float* bv   = (const float*)d_in[9];
    const float* wo   = (const float*)d_in[10];
    const float* bo   = (const float*)d_in[11];
    const float* wf1  = (const float*)d_in[12];
    const float* bf1  = (const float*)d_in[13];
    const float* wf2  = (const float*)d_in[14];
    const float* bf2  = (const float*)d_in[15];
    const float* g1   = (const float*)d_in[16];
    const float* be1  = (const float*)d_in[17];
    const float* g2   = (const float*)d_in[18];
    const float* be2  = (const float*)d_in[19];
    const float* wfc1 = (const float*)d_in[20];
    const float* bfc1 = (const float*)d_in[21];
    const float* wfc2 = (const float*)d_in[22];
    const float* bfc2 = (const float*)d_in[23];
    float* out = (float*)d_out;

    float* ws = (float*)d_ws;
    float*    h     = ws;                          // fl [0, 4194304)
    // bf16 q/k/v (BHLD), 4,194,304 ushorts each, in [4194304, 10485760) fl
    ushort_t* q16   = (ushort_t*)(ws + 4194304);
    ushort_t* k16   = q16 + 4194304;
    ushort_t* v16   = q16 + 8388608;
    ushort_t* ctxb  = q16;                         // aliases dead q16
    ushort_t* ffbb  = (ushort_t*)(ws + 6291456);   // aliases dead k16/v16 (+beyond)
    // attn scratch region (4194304 floats), dead outside attention phase;
    // ALSO reused as the 16 MB fp32 C-partial for the split-K LN2 path.
    float*    attnS = ws + 16777216;
    ushort_t* kT16  = (ushort_t*)attnS;            //   fl [0, 2097152): kT bf16
    float*    Mbuf  = attnS + 2097152;             //   fl [2097152, 2228224)
    float*    vmeP  = attnS + 2269184;             //   16384
    float*    OP    = attnS + 2285568;             //   655360
    float*    mP    = attnS + 2940928;             //   20480
    float*    sP    = attnS + 2961408;             //   20480
    uchar_t*  jidx  = (uchar_t*)(attnS + 2981888); //   32768 fl (131072 bytes)
    float*    Cpart = attnS;                       //   16 MB fp32 (LN2 phase only)
    // long-lived scratch — offsets in FLOATS
    float*    scr   = ws + 20971520;
    ushort_t* xb16  = (ushort_t*)scr;              //   fl [0, 262144)
    int*      top   = (int*)(scr + 264192);        //   fl [264192, 266752)
    ushort_t* hb    = (ushort_t*)(scr + 266752);   //   fl [266752, 2363904)
    ushort_t* wqkvT = (ushort_t*)(scr + 2363904);  //   fl [2363904, 2560512)
    ushort_t* woT   = (ushort_t*)(scr + 2560512);  //   fl [2560512, 2626048)
    ushort_t* wf1T  = (ushort_t*)(scr + 2626048);  //   fl [2626048, 2888192)
    ushort_t* wf2T  = (ushort_t*)(scr + 2888192);  //   fl [2888192, 3150336)
    ushort_t* w_inT = (ushort_t*)(scr + 3150336);  //   fl [3150336, 3154432)
    float*    bqkv  = scr + 3154432;               //   fl [3154432, 3155968)

    dim3 blk(256);

    preproc_k<<<dim3(2062), blk, 0, stream>>>(
        wq, wk, wv, wo, wf1, wf2, w_in, bq, bk, bv, x,
        wqkvT, woT, wf1T, wf2T, w_inT, bqkv, xb16);

    gemm_mfma<0,3><<<dim3(BL/128, 2), blk, 0, stream>>>(
        xb16, w_inT, b_in, (void*)h, (void*)hb, BL, DM, 32);

    for (int i = 0; i < 2; ++i) {
        // QKV projection — counted-vmcnt pipeline (K=256)
        gemm_pipe<0,1><<<dim3(BL/128, 6), blk, 0, stream>>>(
            hb, wqkvT + (size_t)i*768*256, bqkv + i*768, (void*)q16, (void*)kT16,
            BL, 768, DM);

        metric2_k<<<dim3(512), dim3(512), 0, stream>>>(
            q16, kT16, idx + (size_t)i*LL*SS, Mbuf, (unsigned int*)jidx);
        topkf_k<<<dim3(BB*NH), dim3(512), 0, stream>>>(Mbuf, top, jidx);
        attnupd_k<<<dim3(BB*NH*NSL), blk, 0, stream>>>(q16, k16, v16, top, mP, sP, OP, vmeP);
        fillcomb_k<<<dim3(512), blk, 0, stream>>>(vmeP, jidx, mP, sP, OP, ctxb);

        // fused O-proj + residual + LN1 (counted-vmcnt 2-phase pipeline)
        gemmln_k<0><<<dim3(BL/32), blk, 0, stream>>>(
            ctxb, woT + (size_t)i*256*256, bo + i*DM, h, hb,
            g1 + i*DM, be1 + i*DM, DM,
            nullptr, nullptr, nullptr, nullptr, nullptr);

        // FF1 — counted-vmcnt pipeline (K=256)
        gemm_pipe<1,2><<<dim3(BL/128, 8), blk, 0, stream>>>(
            hb, wf1T + (size_t)i*1024*256, bf1 + i*DFF, (void*)ffbb, nullptr, BL, DFF, DM);

        // FF2 split-K: gemm_pipe (128^2 tiles, bias folded, fp32 C into dead
        // attn scratch) + streaming LN finish (+ MLP head on last layer).
        gemm_pipe<0,0><<<dim3(BL/128, 2), blk, 0, stream>>>(
            ffbb, wf2T + (size_t)i*256*1024, bf2 + i*DM, (void*)Cpart, nullptr,
            BL, DM, DFF);
        if (i == 1) {
            lnfin_k<1><<<dim3(BL/64), blk, 0, stream>>>(
                Cpart, h, hb, g2 + i*DM, be2 + i*DM,
                wfc1, bfc1, wfc2, bfc2, out);
        } else {
            lnfin_k<0><<<dim3(BL/64), blk, 0, stream>>>(
                Cpart, h, hb, g2 + i*DM, be2 + i*DM,
                nullptr, nullptr, nullptr, nullptr, nullptr);
        }
    }
}

// Round 9
// 422.433 us; speedup vs baseline: 1.0705x; 1.0705x over previous
//
#include <hip/hip_runtime.h>
#include <math.h>

#define BB 8
#define LL 2048
#define DM 256
#define NH 8
#define DH 32
#define DFF 1024
#define SS 40
#define UU 40
#define BL (BB*LL)   // 16384
#define NSL 8        // attnupd L-slices per (b,h)

// attnupd LDS layout constants
#define KP  40       // k/q row stride (ushorts) — 16B-aligned rows for b128
#define VTP 264      // transposed-V / P row stride (ushorts): b128-aligned, ~2-way banks

typedef unsigned short ushort_t;
typedef unsigned char uchar_t;
typedef __attribute__((ext_vector_type(8))) short short8;
typedef __attribute__((ext_vector_type(4))) float f32x4;

__device__ inline ushort_t f2b(float f)
{
    unsigned int u = __float_as_uint(f);
    u += 0x7fff + ((u >> 16) & 1);      // round-to-nearest-even
    return (ushort_t)(u >> 16);
}

__device__ inline float blo(unsigned int u) { return __uint_as_float(u << 16); }
__device__ inline float bhi(unsigned int u) { return __uint_as_float(u & 0xffff0000u); }

__device__ inline void gload16(const void* g, const void* l)
{
    __builtin_amdgcn_global_load_lds(
        (const __attribute__((address_space(1))) unsigned int*)g,
        (__attribute__((address_space(3))) unsigned int*)l, 16, 0, 0);
}

// ---------------------------------------------------------------------------
// bf16 MFMA GEMM, m97 structure. 128x128 tile, BK=32, 256 thr.
// Kept ONLY for the K=32 input projection (K not a multiple of 64).
// OUT_MODE: 0 fp32 RM | 1 QKV scatter | 2 bf16 RM | 3 fp32 RM + bf16 aux
// ---------------------------------------------------------------------------
template<int RELU, int OUT_MODE>
__global__ __launch_bounds__(256)
void gemm_mfma(const ushort_t* __restrict__ A, const ushort_t* __restrict__ Bt,
               const float* __restrict__ bias, void* __restrict__ Cout,
               void* __restrict__ aux, int M, int N, int K)
{
    __shared__ ushort_t Asl[128 * 32];
    __shared__ ushort_t Bsl[128 * 32];

    const int t    = threadIdx.x;
    const int lane = t & 63;
    const int wv   = t >> 6;
    const int row0 = blockIdx.x * 128;
    const int col0 = blockIdx.y * 128;
    const int wr   = (wv >> 1) * 64;
    const int wc   = (wv & 1) * 64;
    const int quad = lane >> 4;
    const int l16  = lane & 15;

    f32x4 acc[4][4];
    #pragma unroll
    for (int i = 0; i < 4; ++i)
        #pragma unroll
        for (int j = 0; j < 4; ++j)
            acc[i][j] = 0.f;

    for (int k0 = 0; k0 < K; k0 += 32) {
        __syncthreads();
        #pragma unroll
        for (int r = 0; r < 2; ++r) {
            int g = r * 256 + t;
            const ushort_t* ga = A  + (size_t)(row0 + (g >> 2)) * K + k0 + (g & 3) * 8;
            const ushort_t* gb = Bt + (size_t)(col0 + (g >> 2)) * K + k0 + (g & 3) * 8;
            int lbase = (r * 256 + wv * 64) * 16;
            gload16(ga, (const char*)Asl + lbase);
            gload16(gb, (const char*)Bsl + lbase);
        }
        __syncthreads();

        short8 af[4], bfr[4];
        #pragma unroll
        for (int mi = 0; mi < 4; ++mi)
            af[mi] = *(const short8*)&Asl[(wr + mi * 16 + l16) * 32 + quad * 8];
        #pragma unroll
        for (int ni = 0; ni < 4; ++ni)
            bfr[ni] = *(const short8*)&Bsl[(wc + ni * 16 + l16) * 32 + quad * 8];
        #pragma unroll
        for (int mi = 0; mi < 4; ++mi)
            #pragma unroll
            for (int ni = 0; ni < 4; ++ni)
                acc[mi][ni] = __builtin_amdgcn_mfma_f32_16x16x32_bf16(
                    af[mi], bfr[ni], acc[mi][ni], 0, 0, 0);
    }

    #pragma unroll
    for (int mi = 0; mi < 4; ++mi) {
        #pragma unroll
        for (int ni = 0; ni < 4; ++ni) {
            int col = col0 + wc + ni * 16 + l16;
            float bb = bias[col];
            #pragma unroll
            for (int r = 0; r < 4; ++r) {
                int row = row0 + wr + mi * 16 + quad * 4 + r;
                float v = acc[mi][ni][r] + bb;
                if (RELU) v = v > 0.f ? v : 0.f;
                if (OUT_MODE == 0) {
                    ((float*)Cout)[(size_t)row * N + col] = v;
                } else if (OUT_MODE == 1) {
                    int tensor = col >> 8;          // 0=q 1=k 2=v
                    int c2 = col & 255;
                    int b  = row >> 11, l = row & (LL - 1);
                    int hh = c2 >> 5,  dh = c2 & 31;
                    int bh = b * NH + hh;
                    size_t bi = (((size_t)bh * LL + l) << 5) + dh;
                    ushort_t vb16 = f2b(v);
                    ((ushort_t*)Cout)[(size_t)tensor * (BB*NH*LL*DH) + bi] = vb16;
                    if (tensor == 1)   // kT[l][bh][d] bf16 for metric
                        ((ushort_t*)aux)[(((size_t)l << 6) + bh) * 32 + dh] = vb16;
                } else if (OUT_MODE == 2) {
                    ((ushort_t*)Cout)[(size_t)row * N + col] = f2b(v);
                } else {
                    ((float*)Cout)[(size_t)row * N + col] = v;
                    ((ushort_t*)aux)[(size_t)row * N + col] = f2b(v);
                }
            }
        }
    }
}

// ---------------------------------------------------------------------------
// gemm_pipe: 128x128 tile, BK=64, dbuf LDS (64 KB, 2 blk/CU) with COUNTED
// vmcnt + raw s_barrier (T3+T4): next tile's 8 gload16/thread stay in flight
// across the barrier. T2 XOR swizzle both-sides. Requires K % 64 == 0.
// ---------------------------------------------------------------------------
template<int RELU, int OUT_MODE>
__global__ __launch_bounds__(256)
void gemm_pipe(const ushort_t* __restrict__ A, const ushort_t* __restrict__ Bt,
               const float* __restrict__ bias, void* __restrict__ Cout,
               void* __restrict__ aux, int M, int N, int K)
{
    __shared__ ushort_t Asl[2][128 * 64];   // 16 KB x2
    __shared__ ushort_t Bsl[2][128 * 64];   // 16 KB x2

    const int t    = threadIdx.x;
    const int lane = t & 63;
    const int wv   = t >> 6;
    const int row0 = blockIdx.x * 128;
    const int col0 = blockIdx.y * 128;
    const int wr   = (wv >> 1) * 64;
    const int wc   = (wv & 1) * 64;
    const int quad = lane >> 4;
    const int l16  = lane & 15;

    f32x4 acc[4][4];
    #pragma unroll
    for (int i = 0; i < 4; ++i)
        #pragma unroll
        for (int j = 0; j < 4; ++j)
            acc[i][j] = 0.f;

    auto stage = [&](int bf, int k0) {
        #pragma unroll
        for (int r = 0; r < 4; ++r) {
            int gg = r * 256 + t;
            int row = gg >> 3, c8 = gg & 7;
            const ushort_t* ga =
                A + (size_t)(row0 + row) * K + k0 + ((c8 ^ (row & 7)) * 8);
            gload16(ga, (const char*)&Asl[bf][0] + (r * 256 + wv * 64) * 16);
        }
        #pragma unroll
        for (int r = 0; r < 4; ++r) {
            int gg = r * 256 + t;
            int row = gg >> 3, c8 = gg & 7;
            const ushort_t* gb =
                Bt + (size_t)(col0 + row) * K + k0 + ((c8 ^ (row & 7)) * 8);
            gload16(gb, (const char*)&Bsl[bf][0] + (r * 256 + wv * 64) * 16);
        }
    };

    const int NS = K >> 6;
    stage(0, 0);

    for (int ks = 0; ks < NS; ++ks) {
        int cur = ks & 1;
        if (ks + 1 < NS) {
            stage(cur ^ 1, (ks + 1) << 6);      // 8 new loads in flight
            asm volatile("s_waitcnt vmcnt(8)" ::: "memory");  // prev tile done
        } else {
            asm volatile("s_waitcnt vmcnt(0)" ::: "memory");
        }
        __builtin_amdgcn_sched_barrier(0);
        __builtin_amdgcn_s_barrier();           // raw: no drain

        #pragma unroll
        for (int kk = 0; kk < 2; ++kk) {
            short8 af[4], bfr[4];
            #pragma unroll
            for (int mi = 0; mi < 4; ++mi) {
                int row = wr + mi * 16 + l16;
                af[mi] = *(const short8*)
                    &Asl[cur][row * 64 + (((kk * 4 + quad) ^ (row & 7)) * 8)];
            }
            #pragma unroll
            for (int ni = 0; ni < 4; ++ni) {
                int row = wc + ni * 16 + l16;
                bfr[ni] = *(const short8*)
                    &Bsl[cur][row * 64 + (((kk * 4 + quad) ^ (row & 7)) * 8)];
            }
            #pragma unroll
            for (int mi = 0; mi < 4; ++mi)
                #pragma unroll
                for (int ni = 0; ni < 4; ++ni)
                    acc[mi][ni] = __builtin_amdgcn_mfma_f32_16x16x32_bf16(
                        af[mi], bfr[ni], acc[mi][ni], 0, 0, 0);
        }

        __builtin_amdgcn_sched_barrier(0);
        __builtin_amdgcn_s_barrier();           // protect cur buf from restage
    }

    #pragma unroll
    for (int mi = 0; mi < 4; ++mi) {
        #pragma unroll
        for (int ni = 0; ni < 4; ++ni) {
            int col = col0 + wc + ni * 16 + l16;
            float bb = bias[col];
            #pragma unroll
            for (int r = 0; r < 4; ++r) {
                int row = row0 + wr + mi * 16 + quad * 4 + r;
                float v = acc[mi][ni][r] + bb;
                if (RELU) v = v > 0.f ? v : 0.f;
                if (OUT_MODE == 0) {
                    ((float*)Cout)[(size_t)row * N + col] = v;
                } else if (OUT_MODE == 1) {
                    int tensor = col >> 8;          // 0=q 1=k 2=v
                    int c2 = col & 255;
                    int b  = row >> 11, l = row & (LL - 1);
                    int hh = c2 >> 5,  dh = c2 & 31;
                    int bh = b * NH + hh;
                    size_t bi = (((size_t)bh * LL + l) << 5) + dh;
                    ushort_t vb16 = f2b(v);
                    ((ushort_t*)Cout)[(size_t)tensor * (BB*NH*LL*DH) + bi] = vb16;
                    if (tensor == 1)   // kT[l][bh][d] bf16 for metric
                        ((ushort_t*)aux)[(((size_t)l << 6) + bh) * 32 + dh] = vb16;
                } else if (OUT_MODE == 2) {
                    ((ushort_t*)Cout)[(size_t)row * N + col] = f2b(v);
                } else {
                    ((float*)Cout)[(size_t)row * N + col] = v;
                    ((ushort_t*)aux)[(size_t)row * N + col] = f2b(v);
                }
            }
        }
    }
}

// ---------------------------------------------------------------------------
// Fused GEMM (Mx256, K param) + residual + LayerNorm (+ optional MLP head):
//   h = LN(h + A@Bt^T + bias) * g + beta ; writes h fp32 + hb bf16.
// 32x256 tile, BK=64, grid M/32 = 512 (2 blocks/CU), counted vmcnt pipeline.
// Used for BOTH LN1 (K=256) and LN2 (K=1024) — round-6's split-K LN2
// regressed (+24us): it swapped cheap L2-resident B-panel re-reads for a
// 16 MB fp32 HBM round-trip + extra launch. Keep fused.
// ---------------------------------------------------------------------------
template<int HEAD>
__global__ __launch_bounds__(256)
void gemmln_k(const ushort_t* __restrict__ A, const ushort_t* __restrict__ Bt,
              const float* __restrict__ bias, float* __restrict__ h,
              ushort_t* __restrict__ hb, const float* __restrict__ g,
              const float* __restrict__ beta, int K,
              const float* __restrict__ w1, const float* __restrict__ b1,
              const float* __restrict__ w2, const float* __restrict__ b2,
              float* __restrict__ out)
{
    __shared__ ushort_t Asl[2][32 * 64];    // 4 KB x2
    __shared__ ushort_t Bsl[2][256 * 64];   // 32 KB x2
    __shared__ float rs[4][32], rs2[4][32]; // 1 KB
    __shared__ float hrowS[256];

    const int t    = threadIdx.x;
    const int lane = t & 63;
    const int wv   = t >> 6;
    const int row0 = blockIdx.x * 32;
    const int wc   = wv * 64;
    const int quad = lane >> 4;
    const int l16  = lane & 15;

    // --- prologue loads (issued before staging: keeps loop vmcnt exact) ---
    float gcol[4], bcol[4], bic[4];
    float hres[2][4][4];
    #pragma unroll
    for (int ni = 0; ni < 4; ++ni) {
        int col = wc + ni * 16 + l16;
        gcol[ni] = g[col];
        bcol[ni] = beta[col];
        bic[ni]  = bias[col];
    }
    #pragma unroll
    for (int mi = 0; mi < 2; ++mi)
        #pragma unroll
        for (int r = 0; r < 4; ++r) {
            int row = row0 + mi * 16 + quad * 4 + r;
            #pragma unroll
            for (int ni = 0; ni < 4; ++ni)
                hres[mi][r][ni] = h[(size_t)row * DM + wc + ni * 16 + l16];
        }

    f32x4 acc[2][4];
    #pragma unroll
    for (int i = 0; i < 2; ++i)
        #pragma unroll
        for (int j = 0; j < 4; ++j)
            acc[i][j] = 0.f;

    // 9 uniform gload16 per thread: 1 A-chunk + 8 B-chunks.
    auto stage = [&](int bf, int k0) {
        {
            int row = t >> 3, c8 = t & 7;
            const ushort_t* ga =
                A + (size_t)(row0 + row) * K + k0 + ((c8 ^ (row & 7)) * 8);
            gload16(ga, (const char*)&Asl[bf][0] + (wv * 64) * 16);
        }
        #pragma unroll
        for (int r = 0; r < 8; ++r) {
            int gg = r * 256 + t;
            int row = gg >> 3, c8 = gg & 7;
            const ushort_t* gb =
                Bt + (size_t)row * K + k0 + ((c8 ^ (row & 7)) * 8);
            gload16(gb, (const char*)&Bsl[bf][0] + (r * 256 + wv * 64) * 16);
        }
    };

    const int NS = K >> 6;
    stage(0, 0);

    for (int ks = 0; ks < NS; ++ks) {
        int cur = ks & 1;
        if (ks + 1 < NS) {
            stage(cur ^ 1, (ks + 1) << 6);      // 9 new loads in flight
            asm volatile("s_waitcnt vmcnt(9)" ::: "memory");  // prev tile done
        } else {
            asm volatile("s_waitcnt vmcnt(0)" ::: "memory");
        }
        __builtin_amdgcn_sched_barrier(0);
        __builtin_amdgcn_s_barrier();           // raw: no drain

        short8 af[2][2], bfr[4][2];
        #pragma unroll
        for (int mi = 0; mi < 2; ++mi) {
            int row = mi * 16 + l16;
            #pragma unroll
            for (int kk = 0; kk < 2; ++kk)
                af[mi][kk] = *(const short8*)
                    &Asl[cur][row * 64 + (((kk * 4 + quad) ^ (row & 7)) * 8)];
        }
        #pragma unroll
        for (int ni = 0; ni < 4; ++ni) {
            int row = wc + ni * 16 + l16;
            #pragma unroll
            for (int kk = 0; kk < 2; ++kk)
                bfr[ni][kk] = *(const short8*)
                    &Bsl[cur][row * 64 + (((kk * 4 + quad) ^ (row & 7)) * 8)];
        }
        #pragma unroll
        for (int kk = 0; kk < 2; ++kk)
            #pragma unroll
            for (int mi = 0; mi < 2; ++mi)
                #pragma unroll
                for (int ni = 0; ni < 4; ++ni)
                    acc[mi][ni] = __builtin_amdgcn_mfma_f32_16x16x32_bf16(
                        af[mi][kk], bfr[ni][kk], acc[mi][ni], 0, 0, 0);

        __builtin_amdgcn_sched_barrier(0);
        __builtin_amdgcn_s_barrier();           // protect cur buf from restage
    }

    // --- epilogue: residual + LN ---
    float ps[2][4], ps2[2][4];
    #pragma unroll
    for (int mi = 0; mi < 2; ++mi) {
        #pragma unroll
        for (int r = 0; r < 4; ++r) {
            float s = 0.f, s2 = 0.f;
            #pragma unroll
            for (int ni = 0; ni < 4; ++ni) {
                float v = acc[mi][ni][r] + bic[ni] + hres[mi][r][ni];
                acc[mi][ni][r] = v;
                s += v;
                s2 += v * v;
            }
            ps[mi][r] = s;
            ps2[mi][r] = s2;
        }
    }
    #pragma unroll
    for (int off = 1; off < 16; off <<= 1) {
        #pragma unroll
        for (int mi = 0; mi < 2; ++mi)
            #pragma unroll
            for (int r = 0; r < 4; ++r) {
                ps[mi][r]  += __shfl_xor(ps[mi][r],  off, 16);
                ps2[mi][r] += __shfl_xor(ps2[mi][r], off, 16);
            }
    }
    if (l16 == 0) {
        #pragma unroll
        for (int mi = 0; mi < 2; ++mi)
            #pragma unroll
            for (int r = 0; r < 4; ++r) {
                int lrow = mi * 16 + quad * 4 + r;
                rs[wv][lrow]  = ps[mi][r];
                rs2[wv][lrow] = ps2[mi][r];
            }
    }
    __syncthreads();

    #pragma unroll
    for (int mi = 0; mi < 2; ++mi) {
        #pragma unroll
        for (int r = 0; r < 4; ++r) {
            int lrow = mi * 16 + quad * 4 + r;
            int row  = row0 + lrow;
            float tot  = rs[0][lrow] + rs[1][lrow] + rs[2][lrow] + rs[3][lrow];
            float tot2 = rs2[0][lrow] + rs2[1][lrow] + rs2[2][lrow] + rs2[3][lrow];
            float mean = tot * (1.f / (float)DM);
            float var  = tot2 * (1.f / (float)DM) - mean * mean;
            float inv  = 1.0f / sqrtf(var + 1e-5f);
            #pragma unroll
            for (int ni = 0; ni < 4; ++ni) {
                int col = wc + ni * 16 + l16;
                float val = (acc[mi][ni][r] - mean) * inv * gcol[ni] + bcol[ni];
                h[(size_t)row * DM + col]  = val;
                hb[(size_t)row * DM + col] = f2b(val);
                if (HEAD && lrow == 31) hrowS[col] = val;   // last row of block
            }
        }
    }

    if (HEAD) {
        __syncthreads();
        if ((blockIdx.x & 63) == 63 && t < 64) {
            int b = blockIdx.x >> 6;
            float s = 0.f;
            for (int kk = 0; kk < DM; ++kk)
                s = fmaf(hrowS[kk], w1[kk * 64 + t], s);
            s += b1[t];
            s = s > 0.f ? s : 0.f;
            float contrib = s * w2[t];
            #pragma unroll
            for (int off = 32; off > 0; off >>= 1)
                contrib += __shfl_down(contrib, off, 64);
            if (t == 0) out[b] = contrib + b2[0];
        }
    }
}

// ---------------------------------------------------------------------------
// fused preproc: all weight transposes+cvt, bias pack, x cvt in ONE dispatch.
// ---------------------------------------------------------------------------
__device__ inline void tcvt_dev(float (*tile)[33], const float* __restrict__ src,
                                ushort_t* __restrict__ dst, int K, int N,
                                int matStride, int bi)
{
    int tilesN = N >> 5;
    int tpm = (K >> 5) * tilesN;
    int m   = bi / tpm;
    int tid = bi % tpm;
    int k0 = (tid / tilesN) << 5, n0 = (tid % tilesN) << 5;
    const float* s = src + (size_t)m * K * N;
    ushort_t*    d = dst + (size_t)m * matStride;
    int r = threadIdx.x >> 5, c = threadIdx.x & 31;
    #pragma unroll
    for (int i = 0; i < 4; ++i)
        tile[r + 8 * i][c] = s[(size_t)(k0 + r + 8 * i) * N + n0 + c];
    __syncthreads();
    #pragma unroll
    for (int i = 0; i < 4; ++i)
        d[(size_t)(n0 + r + 8 * i) * K + k0 + c] = f2b(tile[c][r + 8 * i]);
}

__global__ __launch_bounds__(256)
void preproc_k(const float* __restrict__ wq, const float* __restrict__ wk,
               const float* __restrict__ wv, const float* __restrict__ wo,
               const float* __restrict__ wf1, const float* __restrict__ wf2,
               const float* __restrict__ w_in,
               const float* __restrict__ bq, const float* __restrict__ bk,
               const float* __restrict__ bv, const float* __restrict__ x,
               ushort_t* __restrict__ wqkvT, ushort_t* __restrict__ woT,
               ushort_t* __restrict__ wf1T, ushort_t* __restrict__ wf2T,
               ushort_t* __restrict__ w_inT, float* __restrict__ bqkv,
               ushort_t* __restrict__ xb16)
{
    __shared__ float tile[32][33];
    int b = blockIdx.x;
    if (b < 512) {
        int which = b >> 7, lb = b & 127;
        const float* src = which == 0 ? wq : which == 1 ? wk : which == 2 ? wv : wo;
        ushort_t* dst = which == 0 ? wqkvT : which == 1 ? wqkvT + 65536
                       : which == 2 ? wqkvT + 131072 : woT;
        int stride = which == 3 ? 65536 : 768 * 256;
        tcvt_dev(tile, src, dst, DM, DM, stride, lb);
    } else if (b < 1024) {
        tcvt_dev(tile, wf1, wf1T, DM, DFF, 1024 * 256, b - 512);
    } else if (b < 1536) {
        tcvt_dev(tile, wf2, wf2T, DFF, DM, 256 * 1024, b - 1024);
    } else if (b < 1544) {
        tcvt_dev(tile, w_in, w_inT, 32, DM, 256 * 32, b - 1536);
    } else if (b < 1550) {
        int t = (b - 1544) * 256 + threadIdx.x;
        int i = t / 768, j = t % 768;
        const float* s = j < 256 ? bq : (j < 512 ? bk : bv);
        bqkv[t] = s[i * 256 + (j & 255)];
    } else {
        int tid = (b - 1550) * 256 + threadIdx.x;
        float4 v = ((const float4*)x)[tid];
        unsigned int lo = f2b(v.x) | ((unsigned int)f2b(v.y) << 16);
        unsigned int hi = f2b(v.z) | ((unsigned int)f2b(v.w) << 16);
        ((uint2*)xb16)[tid] = make_uint2(lo, hi);
    }
}

// ---------------------------------------------------------------------------
// metric v6: split-s. 8 waves/block (512 thr): wave (wl, half) computes l =
// blk*4+wl over s-half; partial (max, sum) merged via LDS. grid 512 x 512.
// ---------------------------------------------------------------------------
__global__ __launch_bounds__(512)
void metric2_k(const ushort_t* __restrict__ qb16, const ushort_t* __restrict__ kT,
               const int* __restrict__ idx, float* __restrict__ Mout,
               unsigned int* __restrict__ jidx32)
{
    __shared__ float mxS[2][4][64];
    __shared__ float smS[2][4][64];
    int t = threadIdx.x;
    int w = t >> 6, lane = t & 63;
    int wl = w & 3, half = w >> 2;
    int l = blockIdx.x * 4 + wl;

    if (t < 64) {
        int zb = t >> 3, sel = t & 7;
        int zl = blockIdx.x * 4 + (sel >> 1), hf = sel & 1;
        jidx32[(size_t)(zb * LL + zl) * 2 + hf] = 0;
    }

    float4 q[8];
    {
        const uint4* qr4 = (const uint4*)(qb16 + ((size_t)(lane * LL + l) << 5));
        #pragma unroll
        for (int i = 0; i < 4; ++i) {
            uint4 u = qr4[i];
            q[2 * i]     = make_float4(blo(u.x), bhi(u.x), blo(u.y), bhi(u.y));
            q[2 * i + 1] = make_float4(blo(u.z), bhi(u.z), blo(u.w), bhi(u.w));
        }
    }

    int r40 = idx[l * SS + (lane < SS ? lane : SS - 1)];

    float mx = -3e38f, sm = 0.f;
    int sBeg = half * 20;
    #pragma unroll 4
    for (int s = sBeg; s < sBeg + 20; ++s) {
        int r = __shfl(r40, s, 64);
        const uint4* kr = (const uint4*)(kT + (((size_t)r << 6) + lane) * 32);
        float d = 0.f;
        #pragma unroll
        for (int ww = 0; ww < 4; ++ww) {
            uint4 kv = kr[ww];
            float4 qa = q[2 * ww], qb2 = q[2 * ww + 1];
            d = fmaf(blo(kv.x), qa.x, d);
            d = fmaf(bhi(kv.x), qa.y, d);
            d = fmaf(blo(kv.y), qa.z, d);
            d = fmaf(bhi(kv.y), qa.w, d);
            d = fmaf(blo(kv.z), qb2.x, d);
            d = fmaf(bhi(kv.z), qb2.y, d);
            d = fmaf(blo(kv.w), qb2.z, d);
            d = fmaf(bhi(kv.w), qb2.w, d);
        }
        mx = fmaxf(mx, d);
        sm += d;
    }
    mxS[half][wl][lane] = mx;
    smS[half][wl][lane] = sm;
    __syncthreads();

    if (t < 256) {
        int bh = t >> 2, ls = t & 3;
        float m = fmaxf(mxS[0][ls][bh], mxS[1][ls][bh]);
        float s = smS[0][ls][bh] + smS[1][ls][bh];
        Mout[(size_t)bh * LL + blockIdx.x * 4 + ls] = m - s * (1.0f / (float)LL);
    }
}

// ---------------------------------------------------------------------------
// topkf v2: stage 1 all-pairs rank-select (64 shfl-rotation steps); identical
// selected set to the serial argmax (same strict total order). Stage 2:
// in-LDS rank-select over the 320 candidates.
// ---------------------------------------------------------------------------
__global__ __launch_bounds__(512)
void topkf_k(const float* __restrict__ Mout, int* __restrict__ top,
             uchar_t* __restrict__ jidx)
{
    __shared__ float cvS[320];
    __shared__ int   ciS[320];
    int bh = blockIdx.x;
    int t  = threadIdx.x;
    int lane = t & 63, w = t >> 6;   // w = slice 0..7
    int l0 = w << 8;

    float v[4];
    #pragma unroll
    for (int i = 0; i < 4; ++i)
        v[i] = Mout[(size_t)bh * LL + l0 + i * 64 + lane];

    int rank[4] = {0, 0, 0, 0};
    for (int step = 0; step < 64; ++step) {
        int src = (lane + step) & 63;
        #pragma unroll
        for (int j = 0; j < 4; ++j) {
            float ov = __shfl(v[j], src, 64);
            int   oi = l0 + j * 64 + src;
            #pragma unroll
            for (int i = 0; i < 4; ++i) {
                int mi = l0 + i * 64 + lane;
                rank[i] += (ov > v[i]) || (ov == v[i] && oi < mi);
            }
        }
    }
    #pragma unroll
    for (int i = 0; i < 4; ++i) {
        if (rank[i] < UU) {
            cvS[w * UU + rank[i]] = v[i];
            ciS[w * UU + rank[i]] = l0 + i * 64 + lane;
        }
    }
    __syncthreads();

    for (int c = t; c < 320; c += 512) {
        float mv = cvS[c]; int mi = ciS[c];
        int rnk = 0;
        for (int j = 0; j < 320; ++j)
            rnk += (cvS[j] > mv) || (cvS[j] == mv && ciS[j] < mi);
        if (rnk < UU) {
            top[bh * UU + rnk] = mi;
            int b = bh >> 3, hh = bh & 7;
            jidx[(size_t)(b * LL + mi) * 8 + hh] = (uchar_t)(rnk + 1);
        }
    }
}

// ---------------------------------------------------------------------------
// attnupd v8: REGISTER softmax. QK^T scores stay in VGPRs (dd[3][4] f32x4 =
// exactly the MFMA output); row-max via 16-lane shfl + 4x48 LDS merge (max is
// order-invariant -> bitwise-identical m); exp in registers; P written ONCE
// as bf16 [48][VTP] (25 KB); row sums via shfl + 4x48 merge. LDS 75.6 ->
// 51.6 KB -> 3 blocks/CU.
// ---------------------------------------------------------------------------
__global__ __launch_bounds__(256)
void attnupd_k(const ushort_t* __restrict__ qb16, const ushort_t* __restrict__ kb16,
               const ushort_t* __restrict__ vb16, const int* __restrict__ top,
               float* __restrict__ mP, float* __restrict__ sP,
               float* __restrict__ OP, float* __restrict__ vmeanP)
{
    __shared__ ushort_t qs[48 * KP];     // 3.84 KB (rows 40..47 zero)
    __shared__ ushort_t kv[256 * KP];    // 20 KB (K stride KP; later vT 32xVTP)
    __shared__ ushort_t Pl[48 * VTP];    // 25.3 KB bf16 P
    __shared__ float    wredS[4][48];    // per-wave row partials
    __shared__ float    msh[48];
    __shared__ float    red[8][32];

    int blk = blockIdx.x;
    int sl  = blk & (NSL - 1);
    int bh  = blk >> 3;
    int t   = threadIdx.x;
    int l0  = sl << 8;
    int lane = t & 63, wvx = t >> 6;
    int quad = lane >> 4, l16 = lane & 15;
    const float scale = 0.17677669529663687f;   // 1/sqrt(32)

    // stage q_top bf16 (zero-pad rows 40..47) and k slice bf16
    for (int i = t; i < 48 * 32; i += 256) {
        int j = i >> 5, dcol = i & 31;
        qs[j * KP + dcol] = (j < UU)
            ? qb16[((size_t)(bh * LL + top[bh * UU + j]) << 5) + dcol] : (ushort_t)0;
    }
    {
        const unsigned int* krow =
            (const unsigned int*)(kb16 + ((size_t)(bh * LL + l0 + t) << 5));
        #pragma unroll
        for (int i = 0; i < 16; ++i)
            ((unsigned int*)kv)[t * (KP / 2) + i] = krow[i];
    }
    __syncthreads();

    // QK^T into registers: wave wvx covers N-tiles wvx*4..+3, M-tiles 0..2
    f32x4 dd[3][4];
    {
        short8 afq[3];
        #pragma unroll
        for (int mt = 0; mt < 3; ++mt)
            afq[mt] = *(const short8*)&qs[(mt * 16 + l16) * KP + quad * 8];
        #pragma unroll
        for (int n4 = 0; n4 < 4; ++n4) {
            int nt = wvx * 4 + n4;
            short8 bk = *(const short8*)&kv[(nt * 16 + l16) * KP + quad * 8];
            #pragma unroll
            for (int mt = 0; mt < 3; ++mt) {
                f32x4 z = {0.f, 0.f, 0.f, 0.f};
                dd[mt][n4] = __builtin_amdgcn_mfma_f32_16x16x32_bf16(
                    afq[mt], bk, z, 0, 0, 0);
            }
        }
    }
    // scale + per-row partial max (over this wave's 64 cols)
    float pm[3][4];
    #pragma unroll
    for (int mt = 0; mt < 3; ++mt) {
        #pragma unroll
        for (int n4 = 0; n4 < 4; ++n4)
            dd[mt][n4] *= scale;
        #pragma unroll
        for (int r = 0; r < 4; ++r)
            pm[mt][r] = fmaxf(fmaxf(dd[mt][0][r], dd[mt][1][r]),
                              fmaxf(dd[mt][2][r], dd[mt][3][r]));
    }
    #pragma unroll
    for (int off = 8; off > 0; off >>= 1)
        #pragma unroll
        for (int mt = 0; mt < 3; ++mt)
            #pragma unroll
            for (int r = 0; r < 4; ++r)
                pm[mt][r] = fmaxf(pm[mt][r], __shfl_xor(pm[mt][r], off, 16));
    if (l16 == 0) {
        #pragma unroll
        for (int mt = 0; mt < 3; ++mt)
            #pragma unroll
            for (int r = 0; r < 4; ++r)
                wredS[wvx][mt * 16 + quad * 4 + r] = pm[mt][r];
    }
    __syncthreads();
    if (t < 48)
        msh[t] = fmaxf(fmaxf(wredS[0][t], wredS[1][t]),
                       fmaxf(wredS[2][t], wredS[3][t]));
    __syncthreads();

    // exp in regs -> P bf16 write; row-sum partials; V transpose; vmean
    float ps[3][4];
    #pragma unroll
    for (int mt = 0; mt < 3; ++mt) {
        #pragma unroll
        for (int r = 0; r < 4; ++r) {
            int row = mt * 16 + quad * 4 + r;
            float mm = msh[row];
            float s = 0.f;
            #pragma unroll
            for (int n4 = 0; n4 < 4; ++n4) {
                float e = __expf(dd[mt][n4][r] - mm);
                Pl[row * VTP + wvx * 64 + n4 * 16 + l16] = f2b(e);
                s += e;
            }
            ps[mt][r] = s;
        }
    }
    #pragma unroll
    for (int off = 1; off < 16; off <<= 1)
        #pragma unroll
        for (int mt = 0; mt < 3; ++mt)
            #pragma unroll
            for (int r = 0; r < 4; ++r)
                ps[mt][r] += __shfl_xor(ps[mt][r], off, 16);
    if (l16 == 0) {
        #pragma unroll
        for (int mt = 0; mt < 3; ++mt)
            #pragma unroll
            for (int r = 0; r < 4; ++r)
                wredS[wvx][mt * 16 + quad * 4 + r] = ps[mt][r];
    }
    int j8 = t >> 5, d = t & 31;
    {
        const unsigned int* vrow =
            (const unsigned int*)(vb16 + ((size_t)(bh * LL + l0 + t) << 5));
        #pragma unroll
        for (int i = 0; i < 16; ++i) {
            unsigned int u = vrow[i];
            kv[(2 * i)     * VTP + t] = (ushort_t)(u & 0xffffu);
            kv[(2 * i + 1) * VTP + t] = (ushort_t)(u >> 16);
        }
        const ushort_t* base = vb16 + ((size_t)(bh * LL + l0 + j8 * 32) << 5) + d;
        float s = 0.f;
        #pragma unroll 8
        for (int i = 0; i < 32; ++i)
            s += __uint_as_float((unsigned int)base[(size_t)i << 5] << 16);
        red[j8][d] = s;
    }
    __syncthreads();

    int pq = bh * NSL + sl;
    if (t < UU) {
        sP[pq * UU + t] = (wredS[0][t] + wredS[1][t]) + (wredS[2][t] + wredS[3][t]);
        mP[pq * UU + t] = msh[t];
    }
    if (t < 32) {
        float tot = 0.f;
        #pragma unroll
        for (int p = 0; p < 8; ++p) tot += red[p][t];
        vmeanP[pq * 32 + t] = tot;
    }

    // PV MFMA: waves 0..2 handle M-tile wvx, N = 32 d (2 tiles), K = 256 l
    if (wvx < 3) {
        f32x4 acc0 = {0.f, 0.f, 0.f, 0.f};
        f32x4 acc1 = {0.f, 0.f, 0.f, 0.f};
        #pragma unroll
        for (int ks = 0; ks < 8; ++ks) {
            short8 af = *(const short8*)
                &Pl[(wvx * 16 + l16) * VTP + ks * 32 + quad * 8];
            #pragma unroll
            for (int nt = 0; nt < 2; ++nt) {
                short8 bf = *(const short8*)
                    &kv[(nt * 16 + l16) * VTP + ks * 32 + quad * 8];
                if (nt == 0)
                    acc0 = __builtin_amdgcn_mfma_f32_16x16x32_bf16(af, bf, acc0, 0, 0, 0);
                else
                    acc1 = __builtin_amdgcn_mfma_f32_16x16x32_bf16(af, bf, acc1, 0, 0, 0);
            }
        }
        #pragma unroll
        for (int r = 0; r < 4; ++r) {
            int j = wvx * 16 + quad * 4 + r;
            if (j < UU) {
                OP[((size_t)pq * UU + j) * 32 + l16]      = acc0[r];
                OP[((size_t)pq * UU + j) * 32 + 16 + l16] = acc1[r];
            }
        }
    }
}

// ---------------------------------------------------------------------------
// fillcomb v2: block = (bh, 256-row slice) -> 512 blocks. vmean total summed
// ONCE per block into LDS; rows broadcast from LDS; rare j!=0 rows keep the
// exact old merge path.
// ---------------------------------------------------------------------------
__global__ __launch_bounds__(256)
void fillcomb_k(const float* __restrict__ vmeanP, const uchar_t* __restrict__ jidx,
                const float* __restrict__ mP, const float* __restrict__ sP,
                const float* __restrict__ OP, ushort_t* __restrict__ ctxb)
{
    __shared__ float vs[32];
    int blk = blockIdx.x;
    int bh  = blk >> 3;           // 0..63
    int sl  = blk & 7;
    int l0  = sl << 8;
    int b   = bh >> 3, hh = bh & 7;
    int t   = threadIdx.x;

    if (t < 32) {
        float s = 0.f;
        #pragma unroll
        for (int q = 0; q < NSL; ++q)
            s += vmeanP[(bh * NSL + q) * 32 + t];
        vs[t] = s * (1.f / (float)LL);
    }
    __syncthreads();

    int p  = t & 15;              // pair index within 32-d block
    int d0 = p * 2;
    #pragma unroll 4
    for (int it = 0; it < 16; ++it) {
        int lr   = it * 16 + (t >> 4);             // 0..255
        int rowi = (b << 11) + l0 + lr;            // b*2048 + l
        int j    = (int)jidx[(size_t)rowi * 8 + hh];

        float v0, v1;
        if (j == 0) {
            v0 = vs[d0];
            v1 = vs[d0 + 1];
        } else {
            int jj = j - 1;
            float M = -3e38f;
            #pragma unroll
            for (int q = 0; q < NSL; ++q) M = fmaxf(M, mP[(bh * NSL + q) * UU + jj]);
            float S = 0.f, O0 = 0.f, O1 = 0.f;
            #pragma unroll
            for (int q = 0; q < NSL; ++q) {
                float wgt = __expf(mP[(bh * NSL + q) * UU + jj] - M);
                S  = fmaf(sP[(bh * NSL + q) * UU + jj], wgt, S);
                O0 = fmaf(OP[((size_t)(bh * NSL + q) * UU + jj) * 32 + d0], wgt, O0);
                O1 = fmaf(OP[((size_t)(bh * NSL + q) * UU + jj) * 32 + d0 + 1], wgt, O1);
            }
            v0 = O0 / S;
            v1 = O1 / S;
        }
        ((unsigned int*)ctxb)[(size_t)rowi * 128 + hh * 16 + p] =
            (unsigned int)f2b(v0) | ((unsigned int)f2b(v1) << 16);
    }
}

extern "C" void kernel_launch(void* const* d_in, const int* in_sizes, int n_in,
                              void* d_out, int out_size, void* d_ws, size_t ws_size,
                              hipStream_t stream)
{
    const float* x    = (const float*)d_in[0];
    const int*   idx  = (const int*)  d_in[1];
    const float* w_in = (const float*)d_in[2];
    const float* b_in = (const float*)d_in[3];
    const float* wq   = (const float*)d_in[4];
    const float* bq   = (const float*)d_in[5];
    const float* wk   = (const float*)d_in[6];
    const float* bk   = (const float*)d_in[7];
    const float* wv   = (const float*)d_in[8];
    const float* bv   = (const float*)d_in[9];
    const float* wo   = (const float*)d_in[10];
    const float* bo   = (const float*)d_in[11];
    const float* wf1  = (const float*)d_in[12];
    const float* bf1  = (const float*)d_in[13];
    const float* wf2  = (const float*)d_in[14];
    const float* bf2  = (const float*)d_in[15];
    const float* g1   = (const float*)d_in[16];
    const float* be1  = (const float*)d_in[17];
    const float* g2   = (const float*)d_in[18];
    const float* be2  = (const float*)d_in[19];
    const float* wfc1 = (const float*)d_in[20];
    const float* bfc1 = (const float*)d_in[21];
    const float* wfc2 = (const float*)d_in[22];
    const float* bfc2 = (const float*)d_in[23];
    float* out = (float*)d_out;

    float* ws = (float*)d_ws;
    float*    h     = ws;                          // fl [0, 4194304)
    // bf16 q/k/v (BHLD), 4,194,304 ushorts each, in [4194304, 10485760) fl
    ushort_t* q16   = (ushort_t*)(ws + 4194304);
    ushort_t* k16   = q16 + 4194304;
    ushort_t* v16   = q16 + 8388608;
    ushort_t* ctxb  = q16;                         // aliases dead q16
    ushort_t* ffbb  = (ushort_t*)(ws + 6291456);   // aliases dead k16/v16 (+beyond)
    // attn scratch region (4194304 floats), dead outside attention phase
    float*    attnS = ws + 16777216;
    ushort_t* kT16  = (ushort_t*)attnS;            //   fl [0, 2097152): kT bf16
    float*    Mbuf  = attnS + 2097152;             //   fl [2097152, 2228224)
    float*    vmeP  = attnS + 2269184;             //   16384
    float*    OP    = attnS + 2285568;             //   655360
    float*    mP    = attnS + 2940928;             //   20480
    float*    sP    = attnS + 2961408;             //   20480
    uchar_t*  jidx  = (uchar_t*)(attnS + 2981888); //   32768 fl (131072 bytes)
    // long-lived scratch — offsets in FLOATS
    float*    scr   = ws + 20971520;
    ushort_t* xb16  = (ushort_t*)scr;              //   fl [0, 262144)
    int*      top   = (int*)(scr + 264192);        //   fl [264192, 266752)
    ushort_t* hb    = (ushort_t*)(scr + 266752);   //   fl [266752, 2363904)
    ushort_t* wqkvT = (ushort_t*)(scr + 2363904);  //   fl [2363904, 2560512)
    ushort_t* woT   = (ushort_t*)(scr + 2560512);  //   fl [2560512, 2626048)
    ushort_t* wf1T  = (ushort_t*)(scr + 2626048);  //   fl [2626048, 2888192)
    ushort_t* wf2T  = (ushort_t*)(scr + 2888192);  //   fl [2888192, 3150336)
    ushort_t* w_inT = (ushort_t*)(scr + 3150336);  //   fl [3150336, 3154432)
    float*    bqkv  = scr + 3154432;               //   fl [3154432, 3155968)

    dim3 blk(256);

    preproc_k<<<dim3(2062), blk, 0, stream>>>(
        wq, wk, wv, wo, wf1, wf2, w_in, bq, bk, bv, x,
        wqkvT, woT, wf1T, wf2T, w_inT, bqkv, xb16);

    gemm_mfma<0,3><<<dim3(BL/128, 2), blk, 0, stream>>>(
        xb16, w_inT, b_in, (void*)h, (void*)hb, BL, DM, 32);

    for (int i = 0; i < 2; ++i) {
        // QKV projection — counted-vmcnt pipeline (K=256)
        gemm_pipe<0,1><<<dim3(BL/128, 6), blk, 0, stream>>>(
            hb, wqkvT + (size_t)i*768*256, bqkv + i*768, (void*)q16, (void*)kT16,
            BL, 768, DM);

        metric2_k<<<dim3(512), dim3(512), 0, stream>>>(
            q16, kT16, idx + (size_t)i*LL*SS, Mbuf, (unsigned int*)jidx);
        topkf_k<<<dim3(BB*NH), dim3(512), 0, stream>>>(Mbuf, top, jidx);
        attnupd_k<<<dim3(BB*NH*NSL), blk, 0, stream>>>(q16, k16, v16, top, mP, sP, OP, vmeP);
        fillcomb_k<<<dim3(512), blk, 0, stream>>>(vmeP, jidx, mP, sP, OP, ctxb);

        // fused O-proj + residual + LN1 (counted-vmcnt 2-phase pipeline)
        gemmln_k<0><<<dim3(BL/32), blk, 0, stream>>>(
            ctxb, woT + (size_t)i*256*256, bo + i*DM, h, hb,
            g1 + i*DM, be1 + i*DM, DM,
            nullptr, nullptr, nullptr, nullptr, nullptr);

        // FF1 — counted-vmcnt pipeline (K=256)
        gemm_pipe<1,2><<<dim3(BL/128, 8), blk, 0, stream>>>(
            hb, wf1T + (size_t)i*1024*256, bf1 + i*DFF, (void*)ffbb, nullptr, BL, DFF, DM);

        // fused FF2 + residual + LN2 (+ MLP head on the last layer) — FUSED
        // (round-6 split-K regressed: L2-resident B re-reads were cheaper
        // than the 16 MB fp32 HBM round-trip it introduced)
        if (i == 1) {
            gemmln_k<1><<<dim3(BL/32), blk, 0, stream>>>(
                ffbb, wf2T + (size_t)i*256*1024, bf2 + i*DM, h, hb,
                g2 + i*DM, be2 + i*DM, DFF,
                wfc1, bfc1, wfc2, bfc2, out);
        } else {
            gemmln_k<0><<<dim3(BL/32), blk, 0, stream>>>(
                ffbb, wf2T + (size_t)i*256*1024, bf2 + i*DM, h, hb,
                g2 + i*DM, be2 + i*DM, DFF,
                nullptr, nullptr, nullptr, nullptr, nullptr);
        }
    }
}